// Round 17
// baseline (221.064 us; speedup 1.0000x reference)
//
#include <hip/hip_runtime.h>
#include <hip/hip_bf16.h>

static constexpr int Lc     = 2048;
static constexpr int DIMc   = 512;
static constexpr int HEADSc = 8;
static constexpr int DHEADc = 64;
static constexpr int KSc    = 127;
static constexpr int NQKVc  = 1536;

typedef __attribute__((ext_vector_type(8))) short short8;
typedef __attribute__((ext_vector_type(4))) float f32x4;
typedef unsigned short u16;
typedef unsigned int u32;

__device__ __forceinline__ float b2f(u16 s) {
  return __uint_as_float(((u32)s) << 16);
}
__device__ __forceinline__ u16 f2b(float x) {  // RNE
  u32 u = __float_as_uint(x);
  return (u16)((u + 0x7fffu + ((u >> 16) & 1u)) >> 16);
}
__device__ __forceinline__ void gload16(const void* g, void* l) {
  __builtin_amdgcn_global_load_lds(
      (const __attribute__((address_space(1))) u32*)g,
      (__attribute__((address_space(3))) u32*)l, 16, 0, 0);
}

// ------- fused: weight transposes (blocks 0..3071) + LN1 (blocks 3072..5119)
__global__ __launch_bounds__(256) void prep_kernel(
    const float* __restrict__ w0, const float* __restrict__ w1,
    const float* __restrict__ w2, const float* __restrict__ w3,
    u16* __restrict__ o0, u16* __restrict__ o1, u16* __restrict__ o2,
    u16* __restrict__ o3, const float* __restrict__ xin,
    const float* __restrict__ g, const float* __restrict__ b,
    u16* __restrict__ lnout, u32* __restrict__ bar) {
  __shared__ float tl[32][33];
  __shared__ float rs[4], rq[4], stat[2];
  const int tid = threadIdx.x;
  if (blockIdx.x == 0 && tid < 8) bar[tid] = 0;  // grid-barrier counters
  if (blockIdx.x >= 3072) {  // ---------------- LN1 path
    const int row = blockIdx.x - 3072;
    const float* rp = xin + (size_t)row * DIMc;
    float v0 = rp[tid];
    float v1 = rp[tid + 256];
    float s = v0 + v1;
    float sq = v0 * v0 + v1 * v1;
#pragma unroll
    for (int o = 32; o > 0; o >>= 1) {
      s += __shfl_down(s, o);
      sq += __shfl_down(sq, o);
    }
    const int wid = tid >> 6, lane = tid & 63;
    if (lane == 0) { rs[wid] = s; rq[wid] = sq; }
    __syncthreads();
    if (tid == 0) {
      float S = rs[0] + rs[1] + rs[2] + rs[3];
      float Q = rq[0] + rq[1] + rq[2] + rq[3];
      float m = S / DIMc;
      float var = Q / DIMc - m * m;
      stat[0] = m;
      stat[1] = rsqrtf(var + 1e-5f);
    }
    __syncthreads();
    const float m = stat[0], r = stat[1];
    lnout[(size_t)row * DIMc + tid] = f2b((v0 - m) * r * g[tid] + b[tid]);
    lnout[(size_t)row * DIMc + tid + 256] =
        f2b((v1 - m) * r * g[tid + 256] + b[tid + 256]);
    return;
  }
  // ---------------- wtrans path: W[K][N] -> Wt[N][K] (bf16), vectorized ----
  int t = blockIdx.x;
  const float* W;
  u16* O;
  int K, N;
  if (t < 768)       { W = w0; O = o0; K = 512;  N = 1536; }
  else if (t < 1024) { W = w1; O = o1; K = 512;  N = 512;  t -= 768; }
  else if (t < 2048) { W = w2; O = o2; K = 512;  N = 2048; t -= 1024; }
  else               { W = w3; O = o3; K = 2048; N = 512;  t -= 2048; }
  const int nt = N >> 5;
  const int by = t / nt, bx = t % nt;
  const int c4 = tid & 7, r = tid >> 3;
  {
    const f32x4 v =
        *(const f32x4*)(W + (size_t)(by * 32 + r) * N + bx * 32 + c4 * 4);
    tl[r][c4 * 4 + 0] = v[0];
    tl[r][c4 * 4 + 1] = v[1];
    tl[r][c4 * 4 + 2] = v[2];
    tl[r][c4 * 4 + 3] = v[3];
  }
  __syncthreads();
  {
    ushort4 pk = {f2b(tl[c4 * 4 + 0][r]), f2b(tl[c4 * 4 + 1][r]),
                  f2b(tl[c4 * 4 + 2][r]), f2b(tl[c4 * 4 + 3][r])};
    *(ushort4*)(O + (size_t)(bx * 32 + r) * K + by * 32 + c4 * 4) = pk;
  }
}

// ---- MFMA GEMM: 64x64 tile, 2 waves, BK=64, XOR-swizzle, 2-deep (qkv) -----
__global__ __launch_bounds__(128) void mfma_gemm(
    const u16* __restrict__ A, const u16* __restrict__ Bt,
    const float* __restrict__ bias, u16* __restrict__ C, int M, int N,
    int K) {
  constexpr int BK = 64;
  __shared__ __align__(16) u16 As[2][64 * BK];
  __shared__ __align__(16) u16 Bs[2][64 * BK];
  const int tid = threadIdx.x;
  const int wave = tid >> 6, lane = tid & 63;
  const int m0 = blockIdx.y * 64, n0 = blockIdx.x * 64;
  const int wn = wave * 32;
  const int T = K / BK;

  f32x4 acc[4][2] = {};
  const int fr = lane & 15;
  const int hi = lane >> 4;
  const int lrow = wave * 8 + (lane >> 3);
  const int lcol = ((lane & 7) ^ (lane >> 3)) * 8;

#define STAGE(k0, buf)                                                        \
  {                                                                           \
    _Pragma("unroll") for (int p = 0; p < 4; ++p) {                           \
      gload16(A + (size_t)(m0 + p * 16 + lrow) * K + (k0) + lcol,             \
              &As[buf][p * 1024 + wave * 512]);                               \
      gload16(Bt + (size_t)(n0 + p * 16 + lrow) * K + (k0) + lcol,            \
              &Bs[buf][p * 1024 + wave * 512]);                               \
    }                                                                         \
  }

  STAGE(0, 0);
  STAGE(BK, 1);

  for (int t = 0; t < T; ++t) {
    const int cur = t & 1;
    if (t + 1 < T) {
      asm volatile("s_waitcnt vmcnt(8)" ::: "memory");
    } else {
      asm volatile("s_waitcnt vmcnt(0)" ::: "memory");
    }
    __builtin_amdgcn_s_barrier();

    short8 af[4][2], bf[2][2];
#pragma unroll
    for (int i = 0; i < 4; ++i) {
      const int row = i * 16 + fr;
      const char* rb = (const char*)As[cur] + row * 128;
#pragma unroll
      for (int ks = 0; ks < 2; ++ks)
        af[i][ks] =
            *(const short8*)(rb + ((ks * 64 + hi * 16) ^ ((fr & 7) << 4)));
    }
#pragma unroll
    for (int j = 0; j < 2; ++j) {
      const int row = wn + j * 16 + fr;
      const char* rb = (const char*)Bs[cur] + row * 128;
#pragma unroll
      for (int ks = 0; ks < 2; ++ks)
        bf[j][ks] =
            *(const short8*)(rb + ((ks * 64 + hi * 16) ^ ((fr & 7) << 4)));
    }
    asm volatile("s_waitcnt lgkmcnt(0)" ::: "memory");
    __builtin_amdgcn_sched_barrier(0);
    __builtin_amdgcn_s_barrier();

    if (t + 2 < T) STAGE((t + 2) * BK, cur);

#pragma unroll
    for (int ks = 0; ks < 2; ++ks)
#pragma unroll
      for (int i = 0; i < 4; ++i)
#pragma unroll
        for (int j = 0; j < 2; ++j)
          acc[i][j] = __builtin_amdgcn_mfma_f32_16x16x32_bf16(
              af[i][ks], bf[j][ks], acc[i][j], 0, 0, 0);
  }
#undef STAGE

  const int cl = lane & 15;
  const int rbase = (lane >> 4) * 4;
#pragma unroll
  for (int i = 0; i < 4; ++i) {
#pragma unroll
    for (int j = 0; j < 2; ++j) {
      const int c = n0 + wn + j * 16 + cl;
      const float bv = bias[c];
#pragma unroll
      for (int r = 0; r < 4; ++r) {
        const int row = m0 + i * 16 + rbase + r;
        C[(size_t)row * N + c] = f2b(acc[i][j][r] + bv);
      }
    }
  }
}

// ---------------- MFMA neighborhood attention (unchanged R15) --------------
__global__ __launch_bounds__(256) void attn_mfma(const u16* __restrict__ qkv,
                                                 const float* __restrict__ rpb,
                                                 u16* __restrict__ out) {
  constexpr int NR = 192, NT = 12, PP = 200;
  __shared__ __align__(16) u16 Ks[NR * DHEADc];
  __shared__ __align__(16) u16 Vt[DHEADc * NR];
  __shared__ __align__(16) u16 Ps[4][16 * PP];
  __shared__ float rp[2 * KSc - 1];
  const int h = blockIdx.y, l0 = blockIdx.x * 64, tid = threadIdx.x;
  const int wv = tid >> 6, lane = tid & 63;
  const int fr = lane & 15, hi = lane >> 4;

  int s_min = l0 - 63;
  if (s_min < 0) s_min = 0;
  if (s_min > Lc - KSc) s_min = Lc - KSc;

  for (int i = tid; i < 2 * KSc - 1; i += 256) rp[i] = rpb[h * (2 * KSc - 1) + i];

#pragma unroll
  for (int rd = 0; rd < 6; ++rd) {
    const int linear = rd * 4096 + wv * 1024 + lane * 16;
    const int row = linear >> 7;
    const int seg = (linear >> 4) & 7;
    const int segp = seg ^ (row & 7);
    int gl = s_min + row;
    if (gl > Lc - 1) gl = Lc - 1;
    gload16(qkv + (size_t)gl * NQKVc + DIMc + h * DHEADc + segp * 8,
            (char*)Ks + rd * 4096 + wv * 1024);
  }

#pragma unroll
  for (int rd = 0; rd < 3; ++rd) {
    const int t = rd * 256 + tid;
    const int rpair = t >> 3, seg = t & 7;
    const int r0 = rpair * 2;
    int g0 = s_min + r0, g1 = s_min + r0 + 1;
    if (g0 > Lc - 1) g0 = Lc - 1;
    if (g1 > Lc - 1) g1 = Lc - 1;
    const short8 a =
        *(const short8*)(qkv + (size_t)g0 * NQKVc + 2 * DIMc + h * DHEADc + seg * 8);
    const short8 bq =
        *(const short8*)(qkv + (size_t)g1 * NQKVc + 2 * DIMc + h * DHEADc + seg * 8);
#pragma unroll
    for (int j = 0; j < 8; ++j) {
      const int d = seg * 8 + j;
      int byte = d * (NR * 2) + r0 * 2;
      byte ^= (d & 7) << 4;
      *(u32*)((char*)Vt + byte) =
          ((u32)(u16)a[j]) | (((u32)(u16)bq[j]) << 16);
    }
  }

  const int lq = l0 + wv * 16 + fr;
  short8 qf[2];
#pragma unroll
  for (int ks = 0; ks < 2; ++ks)
    qf[ks] = *(const short8*)(qkv + (size_t)lq * NQKVc + h * DHEADc + ks * 32 + hi * 8);

  __syncthreads();

  f32x4 S[NT] = {};
  __builtin_amdgcn_s_setprio(1);
#pragma unroll
  for (int jt = 0; jt < NT; ++jt) {
#pragma unroll
    for (int ks = 0; ks < 2; ++ks) {
      int byte = (jt * 16 + fr) * 128 + ks * 64 + hi * 16;
      byte ^= (fr & 7) << 4;
      const short8 kf = *(const short8*)((const char*)Ks + byte);
      S[jt] = __builtin_amdgcn_mfma_f32_16x16x32_bf16(qf[ks], kf, S[jt], 0, 0, 0);
    }
  }
  __builtin_amdgcn_s_setprio(0);

  float inv4[4];
#pragma unroll
  for (int r = 0; r < 4; ++r) {
    const int l = l0 + wv * 16 + hi * 4 + r;
    int st = l - 63;
    if (st < 0) st = 0;
    if (st > Lc - KSc) st = Lc - KSc;
    float mx = -3e38f;
#pragma unroll
    for (int jt = 0; jt < NT; ++jt) {
      const int pos = s_min + jt * 16 + fr;
      const int j = pos - st;
      float v = -3e38f;
      if (j >= 0 && j <= KSc - 1) v = S[jt][r] * 0.125f + rp[pos - l + KSc - 1];
      S[jt][r] = v;
      mx = fmaxf(mx, v);
    }
#pragma unroll
    for (int o = 1; o < 16; o <<= 1) mx = fmaxf(mx, __shfl_xor(mx, o));
    float sum = 0.f;
#pragma unroll
    for (int jt = 0; jt < NT; ++jt) {
      const float e = __expf(S[jt][r] - mx);
      S[jt][r] = e;
      sum += e;
    }
#pragma unroll
    for (int o = 1; o < 16; o <<= 1) sum += __shfl_xor(sum, o);
    inv4[r] = 1.f / sum;
  }

#pragma unroll
  for (int jt = 0; jt < NT; ++jt)
#pragma unroll
    for (int r = 0; r < 4; ++r)
      Ps[wv][(hi * 4 + r) * PP + jt * 16 + fr] = f2b(S[jt][r] * inv4[r]);

  f32x4 O[4] = {};
  __builtin_amdgcn_s_setprio(1);
#pragma unroll
  for (int ks = 0; ks < 6; ++ks) {
    const short8 pa =
        *(const short8*)((const char*)Ps[wv] + fr * (PP * 2) + ks * 64 + hi * 16);
#pragma unroll
    for (int dt = 0; dt < 4; ++dt) {
      int byte = (dt * 16 + fr) * (NR * 2) + ks * 64 + hi * 16;
      byte ^= (fr & 7) << 4;
      const short8 vb = *(const short8*)((const char*)Vt + byte);
      O[dt] = __builtin_amdgcn_mfma_f32_16x16x32_bf16(pa, vb, O[dt], 0, 0, 0);
    }
  }
  __builtin_amdgcn_s_setprio(0);

#pragma unroll
  for (int dt = 0; dt < 4; ++dt)
#pragma unroll
    for (int r = 0; r < 4; ++r)
      out[(size_t)(l0 + wv * 16 + hi * 4 + r) * DIMc + h * DHEADc + dt * 16 + fr] =
          f2b(O[dt][r]);
}

// ======== fused tail: proj(ks) -> gridbar -> LN2 -> gridbar -> ff1 ->
// ======== gridbar -> ff2(ks).  256 blocks x 256 thr, 64KB LDS, 1 block/CU.
__device__ __forceinline__ void gridbar(u32* c, int tid) {
  __threadfence();
  __syncthreads();
  if (tid == 0) {
    u32 old = __hip_atomic_fetch_add(c, 1, __ATOMIC_ACQ_REL,
                                     __HIP_MEMORY_SCOPE_AGENT);
    u32 target = (old / 256u + 1u) * 256u;
    while (__hip_atomic_load(c, __ATOMIC_ACQUIRE, __HIP_MEMORY_SCOPE_AGENT) <
           target) {
      __builtin_amdgcn_s_sleep(8);
    }
  }
  __syncthreads();
  __threadfence();
}

__global__ __launch_bounds__(256, 1) void tail_kernel(
    const u16* __restrict__ attnbuf, const u16* __restrict__ wt_proj,
    const float* __restrict__ proj_b, const float* __restrict__ x,
    float* __restrict__ x2, const float* __restrict__ ln2_g,
    const float* __restrict__ ln2_b, u16* __restrict__ lnbuf,
    const u16* __restrict__ wt_ff1, const float* __restrict__ ff1_b,
    u16* __restrict__ ff1buf, const u16* __restrict__ wt_ff2,
    const float* __restrict__ ff2_b, float* __restrict__ outp,
    u32* __restrict__ bar) {
  __shared__ __align__(16) char LB[65536];
  const int tid = threadIdx.x;
  const int wave = tid >> 6, lane = tid & 63;
  const int fr = lane & 15;
  const int hi = lane >> 4;
  const int blk = blockIdx.x;

  // ============ phase 1 + 4 helper: wave-K-split GEMM on a 64x64 tile ======
  // (emitted twice via lambda-like macro to keep register reuse simple)
#define KS_GEMM(Ap, Bp, Kv, biasp, resp, Cp, Nv)                              \
  {                                                                           \
    constexpr int BK = 32;                                                    \
    const int m0 = (blk >> 3) * 64, n0 = (blk & 7) * 64;                      \
    const int kslice = (Kv) >> 2;                                             \
    const int kbeg = wave * kslice;                                           \
    const int T = kslice / BK;                                                \
    char* myb = LB + wave * 16384;                                            \
    f32x4 acc[4][4] = {};                                                     \
    const int lrow = lane >> 2;                                               \
    const int lcol = ((lane & 3) ^ ((lane >> 2) & 3)) * 8;                    \
    for (int s = 0; s < 2; ++s) {                                             \
      _Pragma("unroll") for (int p = 0; p < 4; ++p) {                         \
        gload16((Ap) + (size_t)(m0 + p * 16 + lrow) * (Kv) + kbeg + s * BK +  \
                    lcol,                                                     \
                myb + s * 8192 + p * 1024);                                   \
        gload16((Bp) + (size_t)(n0 + p * 16 + lrow) * (Kv) + kbeg + s * BK +  \
                    lcol,                                                     \
                myb + s * 8192 + 4096 + p * 1024);                            \
      }                                                                       \
    }                                                                         \
    for (int t = 0; t < T; ++t) {                                             \
      const int cur = t & 1;                                                  \
      if (t + 1 < T) {                                                        \
        asm volatile("s_waitcnt vmcnt(8)" ::: "memory");                      \
      } else {                                                                \
        asm volatile("s_waitcnt vmcnt(0)" ::: "memory");                      \
      }                                                                       \
      short8 af[4], bf[4];                                                    \
      _Pragma("unroll") for (int i = 0; i < 4; ++i) {                         \
        const char* rb = myb + cur * 8192 + (i * 16 + fr) * 64;               \
        af[i] = *(const short8*)(rb + ((hi * 16) ^ ((fr & 3) << 4)));         \
      }                                                                       \
      _Pragma("unroll") for (int j = 0; j < 4; ++j) {                         \
        const char* rb = myb + cur * 8192 + 4096 + (j * 16 + fr) * 64;        \
        bf[j] = *(const short8*)(rb + ((hi * 16) ^ ((fr & 3) << 4)));         \
      }                                                                       \
      asm volatile("s_waitcnt lgkmcnt(0)" ::: "memory");                      \
      __builtin_amdgcn_sched_barrier(0);                                      \
      if (t + 2 < T) {                                                        \
        _Pragma("unroll") for (int p = 0; p < 4; ++p) {                       \
          gload16((Ap) + (size_t)(m0 + p * 16 + lrow) * (Kv) + kbeg +         \
                      (t + 2) * BK + lcol,                                    \
                  myb + cur * 8192 + p * 1024);                               \
          gload16((Bp) + (size_t)(n0 + p * 16 + lrow) * (Kv) + kbeg +         \
                      (t + 2) * BK + lcol,                                    \
                  myb + cur * 8192 + 4096 + p * 1024);                        \
        }                                                                     \
      }                                                                       \
      __builtin_amdgcn_s_setprio(1);                                          \
      _Pragma("unroll") for (int i = 0; i < 4; ++i)                           \
          _Pragma("unroll") for (int j = 0; j < 4; ++j) acc[i][j] =           \
          __builtin_amdgcn_mfma_f32_16x16x32_bf16(af[i], bf[j], acc[i][j],    \
                                                  0, 0, 0);                   \
      __builtin_amdgcn_s_setprio(0);                                          \
    }                                                                         \
    __syncthreads();                                                          \
    float* red = (float*)LB;                                                  \
    const int rbase = hi * 4;                                                 \
    _Pragma("unroll") for (int i = 0; i < 4; ++i)                             \
        _Pragma("unroll") for (int j = 0; j < 4; ++j)                         \
        _Pragma("unroll") for (int r = 0; r < 4; ++r)                         \
        red[wave * 4096 + (i * 16 + rbase + r) * 64 + j * 16 + fr] =          \
        acc[i][j][r];                                                         \
    __syncthreads();                                                          \
    _Pragma("unroll") for (int q = 0; q < 4; ++q) {                           \
      const int idx = q * 1024 + tid * 4;                                     \
      const int row = idx >> 6, col = idx & 63;                               \
      f32x4 s = *(const f32x4*)&red[idx];                                     \
      _Pragma("unroll") for (int w = 1; w < 4; ++w) s +=                      \
          *(const f32x4*)&red[w * 4096 + idx];                                \
      const f32x4 bb = *(const f32x4*)&(biasp)[n0 + col];                     \
      const size_t o = (size_t)(m0 + row) * (Nv) + n0 + col;                  \
      const f32x4 rr = *(const f32x4*)&(resp)[o];                             \
      s += bb + rr;                                                           \
      *(f32x4*)&(Cp)[o] = s;                                                  \
    }                                                                         \
  }

  // ---- phase 1: proj (K=512) -> x2 ---------------------------------------
  KS_GEMM(attnbuf, wt_proj, DIMc, proj_b, x, x2, DIMc);
  gridbar(bar + 0, tid);

  // ---- phase 2: LN2, 8 rows per block ------------------------------------
  {
    __shared__ float rs[4], rq[4], stat[2];
    for (int rr = 0; rr < 8; ++rr) {
      const int row = blk * 8 + rr;
      const size_t base = (size_t)row * DIMc;
      const float v0 = x2[base + tid];
      const float v1 = x2[base + tid + 256];
      float s = v0 + v1;
      float sq = v0 * v0 + v1 * v1;
#pragma unroll
      for (int o = 32; o > 0; o >>= 1) {
        s += __shfl_down(s, o);
        sq += __shfl_down(sq, o);
      }
      if (lane == 0) { rs[wave] = s; rq[wave] = sq; }
      __syncthreads();
      if (tid == 0) {
        float S = rs[0] + rs[1] + rs[2] + rs[3];
        float Q = rq[0] + rq[1] + rq[2] + rq[3];
        float m = S / DIMc;
        float var = Q / DIMc - m * m;
        stat[0] = m;
        stat[1] = rsqrtf(var + 1e-5f);
      }
      __syncthreads();
      const float m = stat[0], r = stat[1];
      lnbuf[base + tid] = f2b((v0 - m) * r * ln2_g[tid] + ln2_b[tid]);
      lnbuf[base + tid + 256] =
          f2b((v1 - m) * r * ln2_g[tid + 256] + ln2_b[tid + 256]);
      __syncthreads();
    }
  }
  gridbar(bar + 1, tid);

  // ---- phase 3: ff1 (2 groups x 2 tiles, 2-wave pipeline, bias+GELU) ------
  {
    constexpr int BK = 64, K = DIMc, N = 4 * DIMc;
    const int grp = wave >> 1;       // 0,1
    const int gw = wave & 1;         // wave within group
    u16* As = (u16*)(LB + grp * 32768);
    u16* Bs = (u16*)(LB + grp * 32768 + 16384);
    const int wn = gw * 32;
    const int lrow = gw * 8 + (lane >> 3);
    const int lcol = ((lane & 7) ^ (lane >> 3)) * 8;
    const int T = K / BK;  // 8

    for (int rep = 0; rep < 2; ++rep) {
      const int tile = blk * 4 + grp * 2 + rep;
      const int n0 = (tile & 31) * 64, m0 = (tile >> 5) * 64;
      f32x4 acc[4][2] = {};

#define F1STAGE(k0, buf)                                                      \
  {                                                                           \
    _Pragma("unroll") for (int p = 0; p < 4; ++p) {                           \
      gload16(lnbuf + (size_t)(m0 + p * 16 + lrow) * K + (k0) + lcol,         \
              &As[(buf) * 4096 + p * 1024 + gw * 512]);                       \
      gload16(wt_ff1 + (size_t)(n0 + p * 16 + lrow) * K + (k0) + lcol,        \
              &Bs[(buf) * 4096 + p * 1024 + gw * 512]);                       \
    }                                                                         \
  }
      F1STAGE(0, 0);
      F1STAGE(BK, 1);
      for (int t = 0; t < T; ++t) {
        const int cur = t & 1;
        if (t + 1 < T) {
          asm volatile("s_waitcnt vmcnt(8)" ::: "memory");
        } else {
          asm volatile("s_waitcnt vmcnt(0)" ::: "memory");
        }
        __builtin_amdgcn_s_barrier();  // block-wide; groups run in lockstep

        short8 af[4][2], bf[2][2];
#pragma unroll
        for (int i = 0; i < 4; ++i) {
          const char* rb = (const char*)&As[cur * 4096] + (i * 16 + fr) * 128;
#pragma unroll
          for (int ks = 0; ks < 2; ++ks)
            af[i][ks] =
                *(const short8*)(rb + ((ks * 64 + hi * 16) ^ ((fr & 7) << 4)));
        }
#pragma unroll
        for (int j = 0; j < 2; ++j) {
          const char* rb =
              (const char*)&Bs[cur * 4096] + (wn + j * 16 + fr) * 128;
#pragma unroll
          for (int ks = 0; ks < 2; ++ks)
            bf[j][ks] =
                *(const short8*)(rb + ((ks * 64 + hi * 16) ^ ((fr & 7) << 4)));
        }
        asm volatile("s_waitcnt lgkmcnt(0)" ::: "memory");
        __builtin_amdgcn_sched_barrier(0);
        __builtin_amdgcn_s_barrier();

        if (t + 2 < T) F1STAGE((t + 2) * BK, cur);

#pragma unroll
        for (int ks = 0; ks < 2; ++ks)
#pragma unroll
          for (int i = 0; i < 4; ++i)
#pragma unroll
            for (int j = 0; j < 2; ++j)
              acc[i][j] = __builtin_amdgcn_mfma_f32_16x16x32_bf16(
                  af[i][ks], bf[j][ks], acc[i][j], 0, 0, 0);
      }
#undef F1STAGE

      const int cl = lane & 15;
      const int rbase = (lane >> 4) * 4;
#pragma unroll
      for (int i = 0; i < 4; ++i) {
#pragma unroll
        for (int j = 0; j < 2; ++j) {
          const int c = n0 + wn + j * 16 + cl;
          const float bv = ff1_b[c];
#pragma unroll
          for (int r = 0; r < 4; ++r) {
            const int row = m0 + i * 16 + rbase + r;
            float v = acc[i][j][r] + bv;
            v = 0.5f * v * (1.0f + erff(v * 0.70710678118f));
            ff1buf[(size_t)row * N + c] = f2b(v);
          }
        }
      }
    }
  }
  gridbar(bar + 2, tid);

  // ---- phase 4: ff2 (K=2048) -> out ---------------------------------------
  KS_GEMM(ff1buf, wt_ff2, 4 * DIMc, ff2_b, x2, outp, DIMc);
#undef KS_GEMM
}

// ---------------------------------------------------------------------------
extern "C" void kernel_launch(void* const* d_in, const int* in_sizes, int n_in,
                              void* d_out, int out_size, void* d_ws,
                              size_t ws_size, hipStream_t stream) {
  const float* x      = (const float*)d_in[0];
  const float* ln1_g  = (const float*)d_in[1];
  const float* ln1_b  = (const float*)d_in[2];
  const float* qkv_w  = (const float*)d_in[3];
  const float* qkv_b  = (const float*)d_in[4];
  const float* rpb    = (const float*)d_in[5];
  const float* proj_w = (const float*)d_in[6];
  const float* proj_b = (const float*)d_in[7];
  const float* ln2_g  = (const float*)d_in[8];
  const float* ln2_b  = (const float*)d_in[9];
  const float* ff1_w  = (const float*)d_in[10];
  const float* ff1_b  = (const float*)d_in[11];
  const float* ff2_w  = (const float*)d_in[12];
  const float* ff2_b  = (const float*)d_in[13];
  float* out = (float*)d_out;

  char* ws = (char*)d_ws;
  u16*   lnbuf   = (u16*)(ws);                         // [0,2) MB
  u16*   qkvbuf  = (u16*)(ws + ((size_t)2  << 20));    // [2,8)
  u16*   attnbuf = (u16*)(ws + ((size_t)8  << 20));    // [8,10)
  float* x2      = (float*)(ws + ((size_t)10 << 20));  // [10,14)
  u16*   ff1buf  = (u16*)(ws + ((size_t)14 << 20));    // [14,22)
  u16*   wt_qkv  = (u16*)(ws + ((size_t)22 << 20));    // [22,23.5)
  u16*   wt_proj = (u16*)(ws + ((size_t)23 << 20) + ((size_t)512 << 10));
  u16*   wt_ff1  = (u16*)(ws + ((size_t)24 << 20));    // [24,26)
  u16*   wt_ff2  = (u16*)(ws + ((size_t)26 << 20));    // [26,28)
  u32*   bar     = (u32*)(ws + ((size_t)30 << 20));    // barrier counters

  // 1) weight transposes + LN1 + barrier-counter init
  prep_kernel<<<5120, 256, 0, stream>>>(qkv_w, proj_w, ff1_w, ff2_w, wt_qkv,
                                        wt_proj, wt_ff1, wt_ff2, x, ln1_g,
                                        ln1_b, lnbuf, bar);
  // 2) QKV GEMM (2-wave, bf16 out)
  mfma_gemm<<<dim3(NQKVc / 64, Lc / 64), 128, 0, stream>>>(
      lnbuf, wt_qkv, qkv_b, qkvbuf, Lc, NQKVc, DIMc);
  // 3) attention (MFMA)
  attn_mfma<<<dim3(Lc / 64, HEADSc), 256, 0, stream>>>(qkvbuf, rpb, attnbuf);
  // 4) fused tail: proj -> LN2 -> ff1 -> ff2 (grid barriers, 256 blocks)
  tail_kernel<<<256, 256, 0, stream>>>(attnbuf, wt_proj, proj_b, x, x2, ln2_g,
                                       ln2_b, lnbuf, wt_ff1, ff1_b, ff1buf,
                                       wt_ff2, ff2_b, out, bar);
}

// Round 18
// 66.864 us; speedup vs baseline: 3.3062x; 3.3062x over previous
//
#include <hip/hip_runtime.h>
#include <hip/hip_bf16.h>

static constexpr int Lc     = 2048;
static constexpr int DIMc   = 512;
static constexpr int HEADSc = 8;
static constexpr int DHEADc = 64;
static constexpr int KSc    = 127;
static constexpr int NQKVc  = 1536;

typedef __attribute__((ext_vector_type(8))) short short8;
typedef __attribute__((ext_vector_type(4))) float f32x4;
typedef unsigned short u16;
typedef unsigned int u32;

__device__ __forceinline__ float b2f(u16 s) {
  return __uint_as_float(((u32)s) << 16);
}
__device__ __forceinline__ u16 f2b(float x) {  // RNE
  u32 u = __float_as_uint(x);
  return (u16)((u + 0x7fffu + ((u >> 16) & 1u)) >> 16);
}
__device__ __forceinline__ void gload16(const void* g, void* l) {
  __builtin_amdgcn_global_load_lds(
      (const __attribute__((address_space(1))) u32*)g,
      (__attribute__((address_space(3))) u32*)l, 16, 0, 0);
}

// ------- fused: weight transposes (blocks 0..3071) + LN1 (blocks 3072..5119)
// transpose vectorized: f32x4 loads, ushort4 stores (G13)
__global__ __launch_bounds__(256) void prep_kernel(
    const float* __restrict__ w0, const float* __restrict__ w1,
    const float* __restrict__ w2, const float* __restrict__ w3,
    u16* __restrict__ o0, u16* __restrict__ o1, u16* __restrict__ o2,
    u16* __restrict__ o3, const float* __restrict__ xin,
    const float* __restrict__ g, const float* __restrict__ b,
    u16* __restrict__ lnout) {
  __shared__ float tl[32][33];
  __shared__ float rs[4], rq[4], stat[2];
  const int tid = threadIdx.x;
  if (blockIdx.x >= 3072) {  // ---------------- LN1 path
    const int row = blockIdx.x - 3072;
    const float* rp = xin + (size_t)row * DIMc;
    float v0 = rp[tid];
    float v1 = rp[tid + 256];
    float s = v0 + v1;
    float sq = v0 * v0 + v1 * v1;
#pragma unroll
    for (int o = 32; o > 0; o >>= 1) {
      s += __shfl_down(s, o);
      sq += __shfl_down(sq, o);
    }
    const int wid = tid >> 6, lane = tid & 63;
    if (lane == 0) { rs[wid] = s; rq[wid] = sq; }
    __syncthreads();
    if (tid == 0) {
      float S = rs[0] + rs[1] + rs[2] + rs[3];
      float Q = rq[0] + rq[1] + rq[2] + rq[3];
      float m = S / DIMc;
      float var = Q / DIMc - m * m;
      stat[0] = m;
      stat[1] = rsqrtf(var + 1e-5f);
    }
    __syncthreads();
    const float m = stat[0], r = stat[1];
    lnout[(size_t)row * DIMc + tid] = f2b((v0 - m) * r * g[tid] + b[tid]);
    lnout[(size_t)row * DIMc + tid + 256] =
        f2b((v1 - m) * r * g[tid + 256] + b[tid + 256]);
    return;
  }
  // ---------------- wtrans path: W[K][N] -> Wt[N][K] (bf16), vectorized ----
  int t = blockIdx.x;
  const float* W;
  u16* O;
  int K, N;
  if (t < 768)       { W = w0; O = o0; K = 512;  N = 1536; }
  else if (t < 1024) { W = w1; O = o1; K = 512;  N = 512;  t -= 768; }
  else if (t < 2048) { W = w2; O = o2; K = 512;  N = 2048; t -= 1024; }
  else               { W = w3; O = o3; K = 2048; N = 512;  t -= 2048; }
  const int nt = N >> 5;
  const int by = t / nt, bx = t % nt;
  const int c4 = tid & 7, r = tid >> 3;  // r: 0..31, c4: 0..7
  {
    const f32x4 v =
        *(const f32x4*)(W + (size_t)(by * 32 + r) * N + bx * 32 + c4 * 4);
    tl[r][c4 * 4 + 0] = v[0];
    tl[r][c4 * 4 + 1] = v[1];
    tl[r][c4 * 4 + 2] = v[2];
    tl[r][c4 * 4 + 3] = v[3];
  }
  __syncthreads();
  {
    ushort4 pk = {f2b(tl[c4 * 4 + 0][r]), f2b(tl[c4 * 4 + 1][r]),
                  f2b(tl[c4 * 4 + 2][r]), f2b(tl[c4 * 4 + 3][r])};
    *(ushort4*)(O + (size_t)(bx * 32 + r) * K + by * 32 + c4 * 4) = pk;
  }
}

// ---------------- pure LayerNorm2: f32 in -> bf16 out ----------------------
__global__ __launch_bounds__(256) void ln2_kernel(const float* __restrict__ in,
                                                  const float* __restrict__ g,
                                                  const float* __restrict__ b,
                                                  u16* __restrict__ out) {
  const int row = blockIdx.x;
  const int tid = threadIdx.x;
  const float* rp = in + (size_t)row * DIMc;
  float v0 = rp[tid];
  float v1 = rp[tid + 256];
  float s = v0 + v1;
  float sq = v0 * v0 + v1 * v1;
  __shared__ float rs[4], rq[4], stat[2];
#pragma unroll
  for (int o = 32; o > 0; o >>= 1) {
    s += __shfl_down(s, o);
    sq += __shfl_down(sq, o);
  }
  const int wid = tid >> 6, lane = tid & 63;
  if (lane == 0) { rs[wid] = s; rq[wid] = sq; }
  __syncthreads();
  if (tid == 0) {
    float S = rs[0] + rs[1] + rs[2] + rs[3];
    float Q = rq[0] + rq[1] + rq[2] + rq[3];
    float m = S / DIMc;
    float var = Q / DIMc - m * m;
    stat[0] = m;
    stat[1] = rsqrtf(var + 1e-5f);
  }
  __syncthreads();
  const float m = stat[0], r = stat[1];
  out[(size_t)row * DIMc + tid] = f2b((v0 - m) * r * g[tid] + b[tid]);
  out[(size_t)row * DIMc + tid + 256] =
      f2b((v1 - m) * r * g[tid + 256] + b[tid + 256]);
}

// ---- MFMA GEMM: 64x64 tile, 2 waves, BK=64, XOR-swizzle, 2-deep -----------
// OP: 0 bias (bf16 out), 1 bias+GELU (bf16 out)
template <int OP, typename OUT_T>
__global__ __launch_bounds__(128) void mfma_gemm(
    const u16* __restrict__ A, const u16* __restrict__ Bt,
    const float* __restrict__ bias, const float* __restrict__ res,
    OUT_T* __restrict__ C, int M, int N, int K) {
  constexpr int BK = 64;
  __shared__ __align__(16) u16 As[2][64 * BK];
  __shared__ __align__(16) u16 Bs[2][64 * BK];
  const int tid = threadIdx.x;
  const int wave = tid >> 6, lane = tid & 63;
  const int m0 = blockIdx.y * 64, n0 = blockIdx.x * 64;
  const int wn = wave * 32;
  const int T = K / BK;

  f32x4 acc[4][2] = {};

  const int fr = lane & 15;
  const int hi = lane >> 4;

  const int lrow = wave * 8 + (lane >> 3);
  const int lcol = ((lane & 7) ^ (lane >> 3)) * 8;

#define STAGE(k0, buf)                                                        \
  {                                                                           \
    _Pragma("unroll") for (int p = 0; p < 4; ++p) {                           \
      gload16(A + (size_t)(m0 + p * 16 + lrow) * K + (k0) + lcol,             \
              &As[buf][p * 1024 + wave * 512]);                               \
      gload16(Bt + (size_t)(n0 + p * 16 + lrow) * K + (k0) + lcol,            \
              &Bs[buf][p * 1024 + wave * 512]);                               \
    }                                                                         \
  }

  STAGE(0, 0);
  STAGE(BK, 1);

  for (int t = 0; t < T; ++t) {
    const int cur = t & 1;
    if (t + 1 < T) {
      asm volatile("s_waitcnt vmcnt(8)" ::: "memory");
    } else {
      asm volatile("s_waitcnt vmcnt(0)" ::: "memory");
    }
    __builtin_amdgcn_s_barrier();  // all waves: stage t resident

    short8 af[4][2], bf[2][2];
#pragma unroll
    for (int i = 0; i < 4; ++i) {
      const int row = i * 16 + fr;
      const char* rb = (const char*)As[cur] + row * 128;
#pragma unroll
      for (int ks = 0; ks < 2; ++ks)
        af[i][ks] =
            *(const short8*)(rb + ((ks * 64 + hi * 16) ^ ((fr & 7) << 4)));
    }
#pragma unroll
    for (int j = 0; j < 2; ++j) {
      const int row = wn + j * 16 + fr;
      const char* rb = (const char*)Bs[cur] + row * 128;
#pragma unroll
      for (int ks = 0; ks < 2; ++ks)
        bf[j][ks] =
            *(const short8*)(rb + ((ks * 64 + hi * 16) ^ ((fr & 7) << 4)));
    }
    asm volatile("s_waitcnt lgkmcnt(0)" ::: "memory");
    __builtin_amdgcn_sched_barrier(0);
    __builtin_amdgcn_s_barrier();  // all waves done reading buf[cur]

    if (t + 2 < T) STAGE((t + 2) * BK, cur);

#pragma unroll
    for (int ks = 0; ks < 2; ++ks)
#pragma unroll
      for (int i = 0; i < 4; ++i)
#pragma unroll
        for (int j = 0; j < 2; ++j)
          acc[i][j] = __builtin_amdgcn_mfma_f32_16x16x32_bf16(
              af[i][ks], bf[j][ks], acc[i][j], 0, 0, 0);
  }
#undef STAGE

  const int cl = lane & 15;
  const int rbase = (lane >> 4) * 4;
#pragma unroll
  for (int i = 0; i < 4; ++i) {
#pragma unroll
    for (int j = 0; j < 2; ++j) {
      const int c = n0 + wn + j * 16 + cl;
      const float bv = bias[c];
#pragma unroll
      for (int r = 0; r < 4; ++r) {
        const int row = m0 + i * 16 + rbase + r;
        float v = acc[i][j][r] + bv;
        if (OP == 1) v = 0.5f * v * (1.0f + erff(v * 0.70710678118f));
        ((u16*)C)[(size_t)row * N + c] = f2b(v);
      }
    }
  }
}

// ---- MFMA GEMM wave-K-split: 4 waves each do full 64x64 tile for K/4 ------
// Self-paced waves (private LDS, no barriers in loop, counted vmcnt) with
// setprio around the MFMA cluster, then LDS reduce. f32 out = sum+bias+res.
__global__ __launch_bounds__(256, 1) void mfma_gemm_ks(
    const u16* __restrict__ A, const u16* __restrict__ Bt,
    const float* __restrict__ bias, const float* __restrict__ res,
    float* __restrict__ C, int M, int N, int K) {
  constexpr int BK = 32;
  __shared__ __align__(16) char LB[65536];
  const int tid = threadIdx.x;
  const int wave = tid >> 6, lane = tid & 63;
  const int m0 = blockIdx.y * 64, n0 = blockIdx.x * 64;
  const int kslice = K >> 2;
  const int kbeg = wave * kslice;
  const int T = kslice / BK;
  char* myb = LB + wave * 16384;

  f32x4 acc[4][4] = {};
  const int fr = lane & 15;
  const int hi = lane >> 4;

  const int lrow = lane >> 2;  // 0..15
  const int lcol = ((lane & 3) ^ ((lane >> 2) & 3)) * 8;  // elem

#define KSTAGE(k0, b)                                                         \
  {                                                                           \
    _Pragma("unroll") for (int p = 0; p < 4; ++p) {                           \
      gload16(A + (size_t)(m0 + p * 16 + lrow) * K + (k0) + lcol,             \
              myb + (b) * 8192 + p * 1024);                                   \
      gload16(Bt + (size_t)(n0 + p * 16 + lrow) * K + (k0) + lcol,            \
              myb + (b) * 8192 + 4096 + p * 1024);                            \
    }                                                                         \
  }

  KSTAGE(kbeg, 0);
  KSTAGE(kbeg + BK, 1);

  for (int t = 0; t < T; ++t) {
    const int cur = t & 1;
    if (t + 1 < T) {
      asm volatile("s_waitcnt vmcnt(8)" ::: "memory");
    } else {
      asm volatile("s_waitcnt vmcnt(0)" ::: "memory");
    }

    short8 af[4], bf[4];
#pragma unroll
    for (int i = 0; i < 4; ++i) {
      const char* rb = myb + cur * 8192 + (i * 16 + fr) * 64;
      af[i] = *(const short8*)(rb + ((hi * 16) ^ ((fr & 3) << 4)));
    }
#pragma unroll
    for (int j = 0; j < 4; ++j) {
      const char* rb = myb + cur * 8192 + 4096 + (j * 16 + fr) * 64;
      bf[j] = *(const short8*)(rb + ((hi * 16) ^ ((fr & 3) << 4)));
    }
    asm volatile("s_waitcnt lgkmcnt(0)" ::: "memory");
    __builtin_amdgcn_sched_barrier(0);

    if (t + 2 < T) KSTAGE(kbeg + (t + 2) * BK, cur);

    __builtin_amdgcn_s_setprio(1);
#pragma unroll
    for (int i = 0; i < 4; ++i)
#pragma unroll
      for (int j = 0; j < 4; ++j)
        acc[i][j] = __builtin_amdgcn_mfma_f32_16x16x32_bf16(af[i], bf[j],
                                                            acc[i][j], 0, 0, 0);
    __builtin_amdgcn_s_setprio(0);
  }
#undef KSTAGE

  // ---- reduce 4 wave-partials (reuse tile LDS as 4 x 4096 f32) ------------
  __syncthreads();
  float* red = (float*)LB;
  const int rbase = hi * 4;
#pragma unroll
  for (int i = 0; i < 4; ++i)
#pragma unroll
    for (int j = 0; j < 4; ++j)
#pragma unroll
      for (int r = 0; r < 4; ++r)
        red[wave * 4096 + (i * 16 + rbase + r) * 64 + j * 16 + fr] =
            acc[i][j][r];
  __syncthreads();
#pragma unroll
  for (int q = 0; q < 4; ++q) {
    const int idx = q * 1024 + tid * 4;
    const int row = idx >> 6, col = idx & 63;
    f32x4 s = *(const f32x4*)&red[idx];
#pragma unroll
    for (int w = 1; w < 4; ++w) s += *(const f32x4*)&red[w * 4096 + idx];
    const f32x4 bb = *(const f32x4*)&bias[n0 + col];
    const size_t o = (size_t)(m0 + row) * N + n0 + col;
    const f32x4 rr = *(const f32x4*)&res[o];
    s += bb + rr;
    *(f32x4*)&C[o] = s;
  }
}

// ---------------- MFMA neighborhood attention: 64 queries x 1 head / block -
__global__ __launch_bounds__(256) void attn_mfma(const u16* __restrict__ qkv,
                                                 const float* __restrict__ rpb,
                                                 u16* __restrict__ out) {
  constexpr int NR = 192, NT = 12, PP = 200;
  __shared__ __align__(16) u16 Ks[NR * DHEADc];   // [r][d], seg ^ (r&7)
  __shared__ __align__(16) u16 Vt[DHEADc * NR];   // [d][r], seg ^ (d&7)
  __shared__ __align__(16) u16 Ps[4][16 * PP];    // per-wave P, stride 200
  __shared__ float rp[2 * KSc - 1];
  const int h = blockIdx.y, l0 = blockIdx.x * 64, tid = threadIdx.x;
  const int wv = tid >> 6, lane = tid & 63;
  const int fr = lane & 15, hi = lane >> 4;

  int s_min = l0 - 63;
  if (s_min < 0) s_min = 0;
  if (s_min > Lc - KSc) s_min = Lc - KSc;

  for (int i = tid; i < 2 * KSc - 1; i += 256) rp[i] = rpb[h * (2 * KSc - 1) + i];

#pragma unroll
  for (int rd = 0; rd < 6; ++rd) {
    const int linear = rd * 4096 + wv * 1024 + lane * 16;  // byte
    const int row = linear >> 7;          // 128B per row
    const int seg = (linear >> 4) & 7;
    const int segp = seg ^ (row & 7);
    int gl = s_min + row;
    if (gl > Lc - 1) gl = Lc - 1;
    gload16(qkv + (size_t)gl * NQKVc + DIMc + h * DHEADc + segp * 8,
            (char*)Ks + rd * 4096 + wv * 1024);
  }

#pragma unroll
  for (int rd = 0; rd < 3; ++rd) {
    const int t = rd * 256 + tid;
    const int rpair = t >> 3, seg = t & 7;
    const int r0 = rpair * 2;
    int g0 = s_min + r0, g1 = s_min + r0 + 1;
    if (g0 > Lc - 1) g0 = Lc - 1;
    if (g1 > Lc - 1) g1 = Lc - 1;
    const short8 a =
        *(const short8*)(qkv + (size_t)g0 * NQKVc + 2 * DIMc + h * DHEADc + seg * 8);
    const short8 bq =
        *(const short8*)(qkv + (size_t)g1 * NQKVc + 2 * DIMc + h * DHEADc + seg * 8);
#pragma unroll
    for (int j = 0; j < 8; ++j) {
      const int d = seg * 8 + j;
      int byte = d * (NR * 2) + r0 * 2;
      byte ^= (d & 7) << 4;
      *(u32*)((char*)Vt + byte) =
          ((u32)(u16)a[j]) | (((u32)(u16)bq[j]) << 16);
    }
  }

  const int lq = l0 + wv * 16 + fr;
  short8 qf[2];
#pragma unroll
  for (int ks = 0; ks < 2; ++ks)
    qf[ks] = *(const short8*)(qkv + (size_t)lq * NQKVc + h * DHEADc + ks * 32 + hi * 8);

  __syncthreads();

  f32x4 S[NT] = {};
  __builtin_amdgcn_s_setprio(1);
#pragma unroll
  for (int jt = 0; jt < NT; ++jt) {
#pragma unroll
    for (int ks = 0; ks < 2; ++ks) {
      int byte = (jt * 16 + fr) * 128 + ks * 64 + hi * 16;
      byte ^= (fr & 7) << 4;
      const short8 kf = *(const short8*)((const char*)Ks + byte);
      S[jt] = __builtin_amdgcn_mfma_f32_16x16x32_bf16(qf[ks], kf, S[jt], 0, 0, 0);
    }
  }
  __builtin_amdgcn_s_setprio(0);

  float inv4[4];
#pragma unroll
  for (int r = 0; r < 4; ++r) {
    const int l = l0 + wv * 16 + hi * 4 + r;
    int st = l - 63;
    if (st < 0) st = 0;
    if (st > Lc - KSc) st = Lc - KSc;
    float mx = -3e38f;
#pragma unroll
    for (int jt = 0; jt < NT; ++jt) {
      const int pos = s_min + jt * 16 + fr;
      const int j = pos - st;
      float v = -3e38f;
      if (j >= 0 && j <= KSc - 1) v = S[jt][r] * 0.125f + rp[pos - l + KSc - 1];
      S[jt][r] = v;
      mx = fmaxf(mx, v);
    }
#pragma unroll
    for (int o = 1; o < 16; o <<= 1) mx = fmaxf(mx, __shfl_xor(mx, o));
    float sum = 0.f;
#pragma unroll
    for (int jt = 0; jt < NT; ++jt) {
      const float e = __expf(S[jt][r] - mx);
      S[jt][r] = e;
      sum += e;
    }
#pragma unroll
    for (int o = 1; o < 16; o <<= 1) sum += __shfl_xor(sum, o);
    inv4[r] = 1.f / sum;
  }

#pragma unroll
  for (int jt = 0; jt < NT; ++jt)
#pragma unroll
    for (int r = 0; r < 4; ++r)
      Ps[wv][(hi * 4 + r) * PP + jt * 16 + fr] = f2b(S[jt][r] * inv4[r]);

  f32x4 O[4] = {};
  __builtin_amdgcn_s_setprio(1);
#pragma unroll
  for (int ks = 0; ks < 6; ++ks) {
    const short8 pa =
        *(const short8*)((const char*)Ps[wv] + fr * (PP * 2) + ks * 64 + hi * 16);
#pragma unroll
    for (int dt = 0; dt < 4; ++dt) {
      int byte = (dt * 16 + fr) * (NR * 2) + ks * 64 + hi * 16;
      byte ^= (fr & 7) << 4;
      const short8 vb = *(const short8*)((const char*)Vt + byte);
      O[dt] = __builtin_amdgcn_mfma_f32_16x16x32_bf16(pa, vb, O[dt], 0, 0, 0);
    }
  }
  __builtin_amdgcn_s_setprio(0);

#pragma unroll
  for (int dt = 0; dt < 4; ++dt)
#pragma unroll
    for (int r = 0; r < 4; ++r)
      out[(size_t)(l0 + wv * 16 + hi * 4 + r) * DIMc + h * DHEADc + dt * 16 + fr] =
          f2b(O[dt][r]);
}

// ---------------------------------------------------------------------------
extern "C" void kernel_launch(void* const* d_in, const int* in_sizes, int n_in,
                              void* d_out, int out_size, void* d_ws,
                              size_t ws_size, hipStream_t stream) {
  const float* x      = (const float*)d_in[0];
  const float* ln1_g  = (const float*)d_in[1];
  const float* ln1_b  = (const float*)d_in[2];
  const float* qkv_w  = (const float*)d_in[3];
  const float* qkv_b  = (const float*)d_in[4];
  const float* rpb    = (const float*)d_in[5];
  const float* proj_w = (const float*)d_in[6];
  const float* proj_b = (const float*)d_in[7];
  const float* ln2_g  = (const float*)d_in[8];
  const float* ln2_b  = (const float*)d_in[9];
  const float* ff1_w  = (const float*)d_in[10];
  const float* ff1_b  = (const float*)d_in[11];
  const float* ff2_w  = (const float*)d_in[12];
  const float* ff2_b  = (const float*)d_in[13];
  float* out = (float*)d_out;

  char* ws = (char*)d_ws;
  u16*   lnbuf   = (u16*)(ws);                         // [0,2) MB
  u16*   qkvbuf  = (u16*)(ws + ((size_t)2  << 20));    // [2,8)
  u16*   attnbuf = (u16*)(ws + ((size_t)8  << 20));    // [8,10)
  float* x2      = (float*)(ws + ((size_t)10 << 20));  // [10,14)
  u16*   ff1buf  = (u16*)(ws + ((size_t)14 << 20));    // [14,22)
  u16*   wt_qkv  = (u16*)(ws + ((size_t)22 << 20));    // [22,23.5)
  u16*   wt_proj = (u16*)(ws + ((size_t)23 << 20) + ((size_t)512 << 10));
  u16*   wt_ff1  = (u16*)(ws + ((size_t)24 << 20));    // [24,26)
  u16*   wt_ff2  = (u16*)(ws + ((size_t)26 << 20));    // [26,28)

  // 1) weight transposes + LN1 (fused, disjoint block ranges)
  prep_kernel<<<5120, 256, 0, stream>>>(qkv_w, proj_w, ff1_w, ff2_w, wt_qkv,
                                        wt_proj, wt_ff1, wt_ff2, x, ln1_g,
                                        ln1_b, lnbuf);
  // 2) QKV GEMM (2-wave, bf16 out)
  mfma_gemm<0, u16><<<dim3(NQKVc / 64, Lc / 64), 128, 0, stream>>>(
      lnbuf, wt_qkv, qkv_b, nullptr, qkvbuf, Lc, NQKVc, DIMc);
  // 3) attention (MFMA)
  attn_mfma<<<dim3(Lc / 64, HEADSc), 256, 0, stream>>>(qkvbuf, rpb, attnbuf);
  // 4) proj GEMM (ks): x2 = attn @ Wp + pb + x (f32 out)
  mfma_gemm_ks<<<dim3(DIMc / 64, Lc / 64), 256, 0, stream>>>(
      attnbuf, wt_proj, proj_b, x, x2, Lc, DIMc, DIMc);
  // 5) LN2 (pure)
  ln2_kernel<<<Lc, 256, 0, stream>>>(x2, ln2_g, ln2_b, lnbuf);
  // 6) FF1 GEMM (2-wave, bias+GELU, bf16 out)
  mfma_gemm<1, u16><<<dim3(4 * DIMc / 64, Lc / 64), 128, 0, stream>>>(
      lnbuf, wt_ff1, ff1_b, nullptr, ff1buf, Lc, 4 * DIMc, DIMc);
  // 7) FF2 GEMM (ks): out = ff1 @ Wf2 + fb + x2 (f32 out)
  mfma_gemm_ks<<<dim3(DIMc / 64, Lc / 64), 256, 0, stream>>>(
      ff1buf, wt_ff2, ff2_b, x2, out, Lc, DIMc, 4 * DIMc);
}